// Round 1
// baseline (144.844 us; speedup 1.0000x reference)
//
#include <hip/hip_runtime.h>
#include <hip/hip_bf16.h>

#define NB 4096
#define DK 1024
#define EPSF 1e-6f

typedef __attribute__((ext_vector_type(8))) short bf16x8_t;
typedef __attribute__((ext_vector_type(4))) float f32x4_t;

// RNE float -> bf16 (values are finite, no NaN concerns)
__device__ __forceinline__ unsigned short f2bf(float f) {
    unsigned u = __float_as_uint(f);
    u += 0x7fffu + ((u >> 16) & 1u);
    return (unsigned short)(u >> 16);
}

// async global->LDS, 16 B per lane. LDS dest is wave-uniform base + lane*16.
__device__ __forceinline__ void async16(const unsigned short* g, unsigned short* lds) {
    __builtin_amdgcn_global_load_lds(
        (const __attribute__((address_space(1))) void*)g,
        (__attribute__((address_space(3))) void*)lds,
        16, 0, 0);
}

// ---------------------------------------------------------------------------
// Kernel 1: per-row normalize of x and y, cast to bf16, and diagonal cos-sim.
// One block (256 threads) per row; 1024 floats/row = exactly one float4/thread.
// ---------------------------------------------------------------------------
__global__ __launch_bounds__(256) void normalize_rows(
    const float* __restrict__ x, const float* __restrict__ y,
    unsigned short* __restrict__ xn, unsigned short* __restrict__ yn,
    float* __restrict__ sdiag)
{
    const int row = blockIdx.x;
    const int t   = threadIdx.x;

    const float4 xv = reinterpret_cast<const float4*>(x + (size_t)row * DK)[t];
    const float4 yv = reinterpret_cast<const float4*>(y + (size_t)row * DK)[t];

    float ssx = xv.x*xv.x + xv.y*xv.y + xv.z*xv.z + xv.w*xv.w;
    float ssy = yv.x*yv.x + yv.y*yv.y + yv.z*yv.z + yv.w*yv.w;
    float sxy = xv.x*yv.x + xv.y*yv.y + xv.z*yv.z + xv.w*yv.w;

    #pragma unroll
    for (int off = 1; off < 64; off <<= 1) {
        ssx += __shfl_xor(ssx, off, 64);
        ssy += __shfl_xor(ssy, off, 64);
        sxy += __shfl_xor(sxy, off, 64);
    }
    __shared__ float red[3][4];
    const int wave = t >> 6;
    if ((t & 63) == 0) { red[0][wave] = ssx; red[1][wave] = ssy; red[2][wave] = sxy; }
    __syncthreads();
    ssx = red[0][0] + red[0][1] + red[0][2] + red[0][3];
    ssy = red[1][0] + red[1][1] + red[1][2] + red[1][3];
    sxy = red[2][0] + red[2][1] + red[2][2] + red[2][3];

    const float invx = 1.0f / fmaxf(sqrtf(ssx), EPSF);
    const float invy = 1.0f / fmaxf(sqrtf(ssy), EPSF);

    ushort4 hx, hy;
    hx.x = f2bf(xv.x * invx); hx.y = f2bf(xv.y * invx);
    hx.z = f2bf(xv.z * invx); hx.w = f2bf(xv.w * invx);
    hy.x = f2bf(yv.x * invy); hy.y = f2bf(yv.y * invy);
    hy.z = f2bf(yv.z * invy); hy.w = f2bf(yv.w * invy);
    reinterpret_cast<ushort4*>(xn + (size_t)row * DK)[t] = hx;
    reinterpret_cast<ushort4*>(yn + (size_t)row * DK)[t] = hy;

    if (t == 0) sdiag[row] = sxy * invx * invy;
}

// ---------------------------------------------------------------------------
// Kernel 2: S = xn * yn^T in 128x128 tiles (bf16 MFMA 16x16x32), fused
// E = exp(S/TAU), accumulate row sums and col sums with one atomicAdd per
// row/col per wave.  BK=32, global_load_lds width-16 staging.
// LDS 16B-group slot swizzle: slot = (kgroup + (row>>1)) & 3  -> 2-way bank
// aliasing on ds_read_b128 (free).
// ---------------------------------------------------------------------------
__global__ __launch_bounds__(256) void gemm_exp_sums(
    const unsigned short* __restrict__ xn, const unsigned short* __restrict__ yn,
    float* __restrict__ rowsum, float* __restrict__ colsum)
{
    __shared__ __align__(16) unsigned short At[128 * 32];  // 8 KB
    __shared__ __align__(16) unsigned short Bt[128 * 32];  // 8 KB

    const int t    = threadIdx.x;
    const int lane = t & 63;
    const int wave = t >> 6;
    const int q    = lane >> 4;    // quad within wave
    const int l15  = lane & 15;

    const int R0 = blockIdx.y * 128;
    const int C0 = blockIdx.x * 128;
    const int wRow = (wave >> 1) * 64;   // wave's 64x64 quadrant
    const int wCol = (wave & 1) * 64;

    f32x4_t acc[4][4];
    #pragma unroll
    for (int i = 0; i < 4; i++)
        #pragma unroll
        for (int j = 0; j < 4; j++)
            acc[i][j] = (f32x4_t){0.f, 0.f, 0.f, 0.f};

    const int slot = (q + ((l15 >> 1) & 3)) & 3;  // read-side swizzled 16B slot

    for (int kb = 0; kb < DK; kb += 32) {
        __syncthreads();
        #pragma unroll
        for (int c = 0; c < 2; ++c) {
            const int rl = wave * 32 + c * 16 + (lane >> 2);     // local row 0..127
            const int kg = ((lane & 3) - (rl >> 1)) & 3;         // source 16B group
            const size_t gA = (size_t)(R0 + rl) * DK + kb + kg * 8;
            const size_t gB = (size_t)(C0 + rl) * DK + kb + kg * 8;
            async16(xn + gA, &At[wave * 1024 + c * 512]);
            async16(yn + gB, &Bt[wave * 1024 + c * 512]);
        }
        __syncthreads();

        bf16x8_t af[4], bfr[4];
        #pragma unroll
        for (int mt = 0; mt < 4; ++mt) {
            const int ar = wRow + mt * 16 + l15;
            af[mt] = *reinterpret_cast<const bf16x8_t*>(&At[ar * 32 + slot * 8]);
        }
        #pragma unroll
        for (int nt = 0; nt < 4; ++nt) {
            const int br = wCol + nt * 16 + l15;
            bfr[nt] = *reinterpret_cast<const bf16x8_t*>(&Bt[br * 32 + slot * 8]);
        }
        #pragma unroll
        for (int mt = 0; mt < 4; ++mt)
            #pragma unroll
            for (int nt = 0; nt < 4; ++nt)
                acc[mt][nt] = __builtin_amdgcn_mfma_f32_16x16x32_bf16(
                    af[mt], bfr[nt], acc[mt][nt], 0, 0, 0);
    }

    // Epilogue: E = exp(S/TAU) = exp2(S * 1/(TAU*ln2)); reduce rows and cols.
    const float kScale = (float)(1.0 / (0.07 * 0.6931471805599453));
    float csum[4] = {0.f, 0.f, 0.f, 0.f};
    #pragma unroll
    for (int mt = 0; mt < 4; ++mt) {
        float rsum[4] = {0.f, 0.f, 0.f, 0.f};
        #pragma unroll
        for (int nt = 0; nt < 4; ++nt) {
            #pragma unroll
            for (int r = 0; r < 4; ++r) {
                const float e = exp2f(acc[mt][nt][r] * kScale);
                rsum[r]  += e;
                csum[nt] += e;
            }
        }
        // 16 lanes sharing a row: reduce over lane&15
        #pragma unroll
        for (int r = 0; r < 4; ++r) {
            float v = rsum[r];
            v += __shfl_xor(v, 1, 64);
            v += __shfl_xor(v, 2, 64);
            v += __shfl_xor(v, 4, 64);
            v += __shfl_xor(v, 8, 64);
            if (l15 == 0)
                atomicAdd(&rowsum[R0 + wRow + mt * 16 + q * 4 + r], v);
        }
    }
    // cols: combine the 4 quads
    #pragma unroll
    for (int nt = 0; nt < 4; ++nt) {
        float v = csum[nt];
        v += __shfl_xor(v, 16, 64);
        v += __shfl_xor(v, 32, 64);
        if (lane < 16)
            atomicAdd(&colsum[C0 + wCol + nt * 16 + l15], v);
    }
}

// ---------------------------------------------------------------------------
// Kernel 3: loss = -1/(2B) [ (2/TAU) * sum(sdiag)
//                            - sum(log(rowsum+extra)) - sum(log(colsum+extra)) ]
// Double accumulation (float tree-sum error ~0.08 would be too close to the
// 0.169 threshold).
// ---------------------------------------------------------------------------
__global__ __launch_bounds__(256) void finalize(
    const float* __restrict__ rowsum, const float* __restrict__ colsum,
    const float* __restrict__ sdiag, float* __restrict__ out)
{
    const float extra = (float)(NB * 1e-6 + 1e-6);
    double local = 0.0;
    for (int i = threadIdx.x; i < NB; i += 256) {
        local += (double)sdiag[i] * (2.0 / 0.07)
               - (double)logf(rowsum[i] + extra)
               - (double)logf(colsum[i] + extra);
    }
    #pragma unroll
    for (int off = 1; off < 64; off <<= 1)
        local += __shfl_xor(local, off, 64);
    __shared__ double dred[4];
    const int wave = threadIdx.x >> 6;
    if ((threadIdx.x & 63) == 0) dred[wave] = local;
    __syncthreads();
    if (threadIdx.x == 0) {
        const double tot = dred[0] + dred[1] + dred[2] + dred[3];
        out[0] = (float)(tot * (-1.0 / (2.0 * NB)));
    }
}

// ---------------------------------------------------------------------------
extern "C" void kernel_launch(void* const* d_in, const int* in_sizes, int n_in,
                              void* d_out, int out_size, void* d_ws, size_t ws_size,
                              hipStream_t stream)
{
    const float* x = (const float*)d_in[0];
    const float* y = (const float*)d_in[1];
    float* out = (float*)d_out;

    char* ws = (char*)d_ws;
    unsigned short* xn = (unsigned short*)ws;                               // 8 MB
    unsigned short* yn = (unsigned short*)(ws + (size_t)8 * 1024 * 1024);   // 8 MB
    float* rowsum = (float*)(ws + (size_t)16 * 1024 * 1024);                // 16 KB
    float* colsum = rowsum + NB;                                            // 16 KB
    float* sdiag  = colsum + NB;                                            // 16 KB

    // ws is re-poisoned 0xAA before every timed launch — zero the accumulators.
    hipMemsetAsync(rowsum, 0, 2 * NB * sizeof(float), stream);

    normalize_rows<<<NB, 256, 0, stream>>>(x, y, xn, yn, sdiag);

    dim3 grid(NB / 128, NB / 128);
    gemm_exp_sums<<<grid, 256, 0, stream>>>(xn, yn, rowsum, colsum);

    finalize<<<1, 256, 0, stream>>>(rowsum, colsum, sdiag, out);
}

// Round 2
// 129.544 us; speedup vs baseline: 1.1181x; 1.1181x over previous
//
#include <hip/hip_runtime.h>
#include <hip/hip_bf16.h>

#define NB 4096
#define DK 1024
#define EPSF 1e-6f

typedef __attribute__((ext_vector_type(8))) short bf16x8_t;
typedef __attribute__((ext_vector_type(4))) float f32x4_t;

// RNE float -> bf16 (values are finite, no NaN concerns)
__device__ __forceinline__ unsigned short f2bf(float f) {
    unsigned u = __float_as_uint(f);
    u += 0x7fffu + ((u >> 16) & 1u);
    return (unsigned short)(u >> 16);
}

// async global->LDS, 16 B per lane. LDS dest is wave-uniform base + lane*16.
__device__ __forceinline__ void async16(const unsigned short* g, unsigned short* lds) {
    __builtin_amdgcn_global_load_lds(
        (const __attribute__((address_space(1))) void*)g,
        (__attribute__((address_space(3))) void*)lds,
        16, 0, 0);
}

// ---------------------------------------------------------------------------
// Kernel 1: wave-per-row normalize of x and y -> bf16, diagonal cos-sim.
// 4 rows per 256-thread block, no __syncthreads, interleaved float4 loads
// (lane-contiguous within each of 4 load rounds -> fully coalesced).
// Also zeroes the rowsum/colsum accumulators (first 32 blocks), replacing
// the separate hipMemsetAsync dispatch.
// ---------------------------------------------------------------------------
__global__ __launch_bounds__(256) void normalize_rows(
    const float* __restrict__ x, const float* __restrict__ y,
    unsigned short* __restrict__ xn, unsigned short* __restrict__ yn,
    float* __restrict__ sdiag, float* __restrict__ zerobuf)
{
    const int t = threadIdx.x;
    const int gid = blockIdx.x * 256 + t;
    if (gid < 2 * NB) zerobuf[gid] = 0.f;   // rowsum+colsum contiguous

    const int wave = t >> 6;
    const int lane = t & 63;
    const int row  = blockIdx.x * 4 + wave;

    const float4* xr = reinterpret_cast<const float4*>(x + (size_t)row * DK);
    const float4* yr = reinterpret_cast<const float4*>(y + (size_t)row * DK);

    float4 xv[4], yv[4];
    float ssx = 0.f, ssy = 0.f, sxy = 0.f;
    #pragma unroll
    for (int j = 0; j < 4; ++j) {
        xv[j] = xr[j * 64 + lane];
        yv[j] = yr[j * 64 + lane];
        ssx += xv[j].x*xv[j].x + xv[j].y*xv[j].y + xv[j].z*xv[j].z + xv[j].w*xv[j].w;
        ssy += yv[j].x*yv[j].x + yv[j].y*yv[j].y + yv[j].z*yv[j].z + yv[j].w*yv[j].w;
        sxy += xv[j].x*yv[j].x + xv[j].y*yv[j].y + xv[j].z*yv[j].z + xv[j].w*yv[j].w;
    }
    #pragma unroll
    for (int off = 1; off < 64; off <<= 1) {
        ssx += __shfl_xor(ssx, off, 64);
        ssy += __shfl_xor(ssy, off, 64);
        sxy += __shfl_xor(sxy, off, 64);
    }
    const float invx = 1.0f / fmaxf(sqrtf(ssx), EPSF);
    const float invy = 1.0f / fmaxf(sqrtf(ssy), EPSF);

    ushort4* xw = reinterpret_cast<ushort4*>(xn + (size_t)row * DK);
    ushort4* yw = reinterpret_cast<ushort4*>(yn + (size_t)row * DK);
    #pragma unroll
    for (int j = 0; j < 4; ++j) {
        ushort4 hx, hy;
        hx.x = f2bf(xv[j].x * invx); hx.y = f2bf(xv[j].y * invx);
        hx.z = f2bf(xv[j].z * invx); hx.w = f2bf(xv[j].w * invx);
        hy.x = f2bf(yv[j].x * invy); hy.y = f2bf(yv[j].y * invy);
        hy.z = f2bf(yv[j].z * invy); hy.w = f2bf(yv[j].w * invy);
        xw[j * 64 + lane] = hx;
        yw[j * 64 + lane] = hy;
    }
    if (lane == 0) sdiag[row] = sxy * invx * invy;
}

// ---------------------------------------------------------------------------
// Kernel 2: S = xn * yn^T, 128x128 tiles, BK=64 (32 MFMA per barrier/wave).
// XOR-swizzled LDS: group g of row r stored at slot g^(r&7); row stride
// 64 shorts (128 B). Write side: lane l of each async16 covers row
// base+(l>>3), source group (l&7)^(l>>3) -> swizzle is lane-pure, so the
// wave-uniform-base+lane*16 DMA lands each group in its swizzled slot.
// Read side: slot=(ks*4+q)^(row&7) -> each 16B slot cluster gets exactly
// 8 of 64 lanes = LDS's 8-clock minimum, zero conflicts.
// Epilogue: E=exp2(S*1/(TAU*ln2)), shuffle-reduced row/col partials,
// one atomicAdd per row/col per wave.
// ---------------------------------------------------------------------------
__global__ __launch_bounds__(256) void gemm_exp_sums(
    const unsigned short* __restrict__ xn, const unsigned short* __restrict__ yn,
    float* __restrict__ rowsum, float* __restrict__ colsum)
{
    __shared__ __align__(16) unsigned short At[128 * 64];  // 16 KB
    __shared__ __align__(16) unsigned short Bt[128 * 64];  // 16 KB

    const int t    = threadIdx.x;
    const int lane = t & 63;
    const int wave = t >> 6;
    const int q    = lane >> 4;    // quad within wave
    const int l15  = lane & 15;

    const int R0 = blockIdx.y * 128;
    const int C0 = blockIdx.x * 128;
    const int wRow = (wave >> 1) * 64;   // wave's 64x64 quadrant
    const int wCol = (wave & 1) * 64;

    f32x4_t acc[4][4];
    #pragma unroll
    for (int i = 0; i < 4; i++)
        #pragma unroll
        for (int j = 0; j < 4; j++)
            acc[i][j] = (f32x4_t){0.f, 0.f, 0.f, 0.f};

    const int r8 = lane >> 3;            // row within 8-row staging chunk
    const int g  = (lane & 7) ^ r8;      // swizzled source 16B-group

    for (int kb = 0; kb < DK; kb += 64) {
        __syncthreads();
        #pragma unroll
        for (int c = 0; c < 4; ++c) {
            const int rl = wave * 32 + c * 8 + r8;          // local row 0..127
            const size_t gOffA = (size_t)(R0 + rl) * DK + kb + g * 8;
            const size_t gOffB = (size_t)(C0 + rl) * DK + kb + g * 8;
            async16(xn + gOffA, &At[(wave * 32 + c * 8) * 64]);
            async16(yn + gOffB, &Bt[(wave * 32 + c * 8) * 64]);
        }
        __syncthreads();

        #pragma unroll
        for (int ks = 0; ks < 2; ++ks) {
            bf16x8_t af[4], bfr[4];
            const int sbase = ks * 4 + q;
            #pragma unroll
            for (int mt = 0; mt < 4; ++mt) {
                const int ar = wRow + mt * 16 + l15;
                const int slot = sbase ^ (ar & 7);
                af[mt] = *reinterpret_cast<const bf16x8_t*>(&At[ar * 64 + slot * 8]);
            }
            #pragma unroll
            for (int nt = 0; nt < 4; ++nt) {
                const int br = wCol + nt * 16 + l15;
                const int slot = sbase ^ (br & 7);
                bfr[nt] = *reinterpret_cast<const bf16x8_t*>(&Bt[br * 64 + slot * 8]);
            }
            #pragma unroll
            for (int mt = 0; mt < 4; ++mt)
                #pragma unroll
                for (int nt = 0; nt < 4; ++nt)
                    acc[mt][nt] = __builtin_amdgcn_mfma_f32_16x16x32_bf16(
                        af[mt], bfr[nt], acc[mt][nt], 0, 0, 0);
        }
    }

    // Epilogue: E = exp(S/TAU) = exp2(S * 1/(TAU*ln2)); reduce rows and cols.
    const float kScale = (float)(1.0 / (0.07 * 0.6931471805599453));
    float csum[4] = {0.f, 0.f, 0.f, 0.f};
    #pragma unroll
    for (int mt = 0; mt < 4; ++mt) {
        float rsum[4] = {0.f, 0.f, 0.f, 0.f};
        #pragma unroll
        for (int nt = 0; nt < 4; ++nt) {
            #pragma unroll
            for (int r = 0; r < 4; ++r) {
                const float e = exp2f(acc[mt][nt][r] * kScale);
                rsum[r]  += e;
                csum[nt] += e;
            }
        }
        #pragma unroll
        for (int r = 0; r < 4; ++r) {
            float v = rsum[r];
            v += __shfl_xor(v, 1, 64);
            v += __shfl_xor(v, 2, 64);
            v += __shfl_xor(v, 4, 64);
            v += __shfl_xor(v, 8, 64);
            if (l15 == 0)
                atomicAdd(&rowsum[R0 + wRow + mt * 16 + q * 4 + r], v);
        }
    }
    #pragma unroll
    for (int nt = 0; nt < 4; ++nt) {
        float v = csum[nt];
        v += __shfl_xor(v, 16, 64);
        v += __shfl_xor(v, 32, 64);
        if (lane < 16)
            atomicAdd(&colsum[C0 + wCol + nt * 16 + l15], v);
    }
}

// ---------------------------------------------------------------------------
// Kernel 3: loss = -1/(2B) [ (2/TAU) * sum(sdiag)
//                            - sum(log(rowsum+extra)) - sum(log(colsum+extra)) ]
// Double accumulation (float tree-sum error would be too close to threshold).
// ---------------------------------------------------------------------------
__global__ __launch_bounds__(1024) void finalize(
    const float* __restrict__ rowsum, const float* __restrict__ colsum,
    const float* __restrict__ sdiag, float* __restrict__ out)
{
    const float extra = (float)(NB * 1e-6 + 1e-6);
    double local = 0.0;
    for (int i = threadIdx.x; i < NB; i += 1024) {
        local += (double)sdiag[i] * (2.0 / 0.07)
               - (double)logf(rowsum[i] + extra)
               - (double)logf(colsum[i] + extra);
    }
    #pragma unroll
    for (int off = 1; off < 64; off <<= 1)
        local += __shfl_xor(local, off, 64);
    __shared__ double dred[16];
    const int wave = threadIdx.x >> 6;
    if ((threadIdx.x & 63) == 0) dred[wave] = local;
    __syncthreads();
    if (threadIdx.x == 0) {
        double tot = 0.0;
        #pragma unroll
        for (int w = 0; w < 16; ++w) tot += dred[w];
        out[0] = (float)(tot * (-1.0 / (2.0 * NB)));
    }
}

// ---------------------------------------------------------------------------
extern "C" void kernel_launch(void* const* d_in, const int* in_sizes, int n_in,
                              void* d_out, int out_size, void* d_ws, size_t ws_size,
                              hipStream_t stream)
{
    const float* x = (const float*)d_in[0];
    const float* y = (const float*)d_in[1];
    float* out = (float*)d_out;

    char* ws = (char*)d_ws;
    unsigned short* xn = (unsigned short*)ws;                               // 8 MB
    unsigned short* yn = (unsigned short*)(ws + (size_t)8 * 1024 * 1024);   // 8 MB
    float* rowsum = (float*)(ws + (size_t)16 * 1024 * 1024);                // 16 KB
    float* colsum = rowsum + NB;                                            // 16 KB
    float* sdiag  = colsum + NB;                                            // 16 KB

    normalize_rows<<<NB / 4, 256, 0, stream>>>(x, y, xn, yn, sdiag, rowsum);

    dim3 grid(NB / 128, NB / 128);
    gemm_exp_sums<<<grid, 256, 0, stream>>>(xn, yn, rowsum, colsum);

    finalize<<<1, 1024, 0, stream>>>(rowsum, colsum, sdiag, out);
}